// Round 1
// baseline (199.523 us; speedup 1.0000x reference)
//
#include <hip/hip_runtime.h>

// Problem constants
#define Bn  4
#define Cc  64      // channels
#define ICc 32      // inner channels
#define Hh  128
#define Ww  128
#define Nn  (Hh*Ww)     // 16384
#define Hp  (Hh/2)      // 64 pooled rows
#define Wp  (Ww/2)      // 64 pooled cols
#define Mm  (Hp*Wp)     // 4096 pooled positions

// ---------------------------------------------------------------------------
// Kernel 1: fused 1x1 conv + 2x2 maxpool for phi (from ref) and g (from ref_align)
// grid (Hp, B, 2), block 128. Thread t: pw = t>>1, row-parity r = t&1.
// Each thread computes all 32 conv channels at 2 horizontal pixels (float2 load),
// maxes them, then maxes vertically with its shfl-pair lane.
// ---------------------------------------------------------------------------
__global__ __launch_bounds__(128) void conv_pool_kernel(
    const float* __restrict__ ref, const float* __restrict__ ref_align,
    const float* __restrict__ phi_w, const float* __restrict__ phi_b,
    const float* __restrict__ g_w,   const float* __restrict__ g_b,
    float* __restrict__ P, float* __restrict__ G)
{
    const int z = blockIdx.z;
    const float* in   = z ? ref_align : ref;
    const float* wmat = z ? g_w  : phi_w;
    const float* bias = z ? g_b  : phi_b;
    float* outp       = z ? G    : P;

    __shared__ float sw[ICc * Cc];
    __shared__ float sb[ICc];
    for (int idx = threadIdx.x; idx < ICc * Cc; idx += 128) sw[idx] = wmat[idx];
    if (threadIdx.x < ICc) sb[threadIdx.x] = bias[threadIdx.x];
    __syncthreads();

    const int tid = threadIdx.x;
    const int pw  = tid >> 1;
    const int r   = tid & 1;
    const int ph  = blockIdx.x;
    const int b   = blockIdx.y;
    const int hh  = 2 * ph + r;

    const float2* xrow = (const float2*)(in + ((size_t)b * Cc * Hh + hh) * Ww);
    const int cstride2 = (Hh * Ww) / 2;   // channel stride in float2

    float acc0[ICc], acc1[ICc];
    #pragma unroll
    for (int i = 0; i < ICc; ++i) { acc0[i] = sb[i]; acc1[i] = sb[i]; }

    #pragma unroll 4
    for (int c = 0; c < Cc; ++c) {
        float2 v = xrow[c * cstride2 + pw];
        #pragma unroll
        for (int i = 0; i < ICc; ++i) {
            acc0[i] = fmaf(sw[i * Cc + c], v.x, acc0[i]);
            acc1[i] = fmaf(sw[i * Cc + c], v.y, acc1[i]);
        }
    }

    const int m = ph * Wp + pw;
    #pragma unroll
    for (int i = 0; i < ICc; ++i) {
        float mx = fmaxf(acc0[i], acc1[i]);
        mx = fmaxf(mx, __shfl_xor(mx, 1, 64));   // vertical max (pair lanes same wave)
        if (r == 0) outp[((size_t)(b * ICc + i)) * Mm + m] = mx;
    }
}

// ---------------------------------------------------------------------------
// Kernel 2: A[b,i,j] = sum_m G[b,i,m] * P[b,j,m].  grid (IC, B), block 256.
// ---------------------------------------------------------------------------
__global__ __launch_bounds__(256) void gram_kernel(
    const float* __restrict__ P, const float* __restrict__ G, float* __restrict__ A)
{
    const int b = blockIdx.y, i = blockIdx.x;
    const float* Gi = G + ((size_t)(b * ICc + i)) * Mm;
    const float* Pb = P + (size_t)b * ICc * Mm;

    float acc[ICc];
    #pragma unroll
    for (int j = 0; j < ICc; ++j) acc[j] = 0.f;

    for (int m = threadIdx.x; m < Mm; m += 256) {
        float gv = Gi[m];
        #pragma unroll
        for (int j = 0; j < ICc; ++j) acc[j] = fmaf(gv, Pb[j * Mm + m], acc[j]);
    }

    // butterfly reduce across the 64-lane wave
    #pragma unroll
    for (int j = 0; j < ICc; ++j) {
        #pragma unroll
        for (int off = 32; off > 0; off >>= 1)
            acc[j] += __shfl_xor(acc[j], off, 64);
    }

    __shared__ float red[4][ICc];
    const int lane = threadIdx.x & 63, wid = threadIdx.x >> 6;
    if (lane == 0)
        for (int j = 0; j < ICc; ++j) red[wid][j] = acc[j];
    __syncthreads();

    if (threadIdx.x < ICc) {
        float s = red[0][threadIdx.x] + red[1][threadIdx.x]
                + red[2][threadIdx.x] + red[3][threadIdx.x];
        A[((size_t)(b * ICc + i)) * ICc + threadIdx.x] = s;
    }
}

// ---------------------------------------------------------------------------
// Kernel 3: per-batch fused matrix  M'[o,c] = (W_w @ (A/N) @ theta_w)[o,c] + (o==c)
//           and bias v[o] = (W_w @ (A/N) @ theta_b)[o] + W_b[o].
// grid B, block 64 (thread = output channel o). Tiny.
// ---------------------------------------------------------------------------
__global__ __launch_bounds__(64) void combine_kernel(
    const float* __restrict__ A, const float* __restrict__ theta_w,
    const float* __restrict__ theta_b, const float* __restrict__ W_w,
    const float* __restrict__ W_b, float* __restrict__ Mp)
{
    const int b = blockIdx.x, o = threadIdx.x;
    __shared__ float sA[ICc * ICc];
    for (int idx = threadIdx.x; idx < ICc * ICc; idx += 64)
        sA[idx] = A[(size_t)b * ICc * ICc + idx];
    __syncthreads();

    float T[ICc];
    #pragma unroll
    for (int j = 0; j < ICc; ++j) T[j] = 0.f;
    for (int i = 0; i < ICc; ++i) {
        float wv = W_w[o * ICc + i];
        #pragma unroll
        for (int j = 0; j < ICc; ++j) T[j] = fmaf(wv, sA[i * ICc + j], T[j]);
    }

    const float invN = 1.f / (float)Nn;
    float* Mb = Mp + (size_t)b * (Cc * Cc + Cc);
    for (int c = 0; c < Cc; ++c) {
        float s = 0.f;
        #pragma unroll
        for (int j = 0; j < ICc; ++j) s = fmaf(T[j], theta_w[j * Cc + c], s);
        Mb[o * Cc + c] = s * invN + (o == c ? 1.f : 0.f);
    }
    float v = 0.f;
    #pragma unroll
    for (int j = 0; j < ICc; ++j) v = fmaf(T[j], theta_b[j], v);
    Mb[Cc * Cc + o] = v * invN + W_b[o];
}

// ---------------------------------------------------------------------------
// Kernel 4: out[b,:,n] = M'_b @ x[b,:,n] + v_b   (residual folded into M').
// grid (N/256, B), block 256; one thread per spatial position.
// ---------------------------------------------------------------------------
__global__ __launch_bounds__(256) void apply_kernel(
    const float* __restrict__ x, const float* __restrict__ Mp, float* __restrict__ out)
{
    const int b = blockIdx.y;
    __shared__ float sM[Cc * Cc];
    __shared__ float sv[Cc];
    const float* Mb = Mp + (size_t)b * (Cc * Cc + Cc);
    for (int idx = threadIdx.x; idx < Cc * Cc; idx += 256) sM[idx] = Mb[idx];
    if (threadIdx.x < Cc) sv[threadIdx.x] = Mb[Cc * Cc + threadIdx.x];
    __syncthreads();

    const int n = blockIdx.x * 256 + threadIdx.x;
    const float* xb = x   + (size_t)b * Cc * Nn;
    float*       ob = out + (size_t)b * Cc * Nn;

    float acc[Cc];
    #pragma unroll
    for (int o = 0; o < Cc; ++o) acc[o] = sv[o];

    #pragma unroll 4
    for (int c = 0; c < Cc; ++c) {
        float xv = xb[c * Nn + n];
        #pragma unroll
        for (int o = 0; o < Cc; ++o) acc[o] = fmaf(sM[o * Cc + c], xv, acc[o]);
    }

    #pragma unroll
    for (int o = 0; o < Cc; ++o) ob[o * Nn + n] = acc[o];
}

// ---------------------------------------------------------------------------
extern "C" void kernel_launch(void* const* d_in, const int* in_sizes, int n_in,
                              void* d_out, int out_size, void* d_ws, size_t ws_size,
                              hipStream_t stream) {
    const float* target    = (const float*)d_in[0];
    const float* ref       = (const float*)d_in[1];
    const float* ref_align = (const float*)d_in[2];
    const float* theta_w   = (const float*)d_in[3];
    const float* theta_b   = (const float*)d_in[4];
    const float* phi_w     = (const float*)d_in[5];
    const float* phi_b     = (const float*)d_in[6];
    const float* g_w       = (const float*)d_in[7];
    const float* g_b       = (const float*)d_in[8];
    const float* W_w       = (const float*)d_in[9];
    const float* W_b       = (const float*)d_in[10];
    float* out = (float*)d_out;

    // workspace layout (floats): P[B*IC*M] | G[B*IC*M] | A[B*IC*IC] | Mp[B*(C*C+C)]
    float* ws = (float*)d_ws;
    float* P  = ws;
    float* G  = P + (size_t)Bn * ICc * Mm;
    float* A  = G + (size_t)Bn * ICc * Mm;
    float* Mp = A + (size_t)Bn * ICc * ICc;

    conv_pool_kernel<<<dim3(Hp, Bn, 2), 128, 0, stream>>>(ref, ref_align,
                                                          phi_w, phi_b, g_w, g_b, P, G);
    gram_kernel<<<dim3(ICc, Bn), 256, 0, stream>>>(P, G, A);
    combine_kernel<<<Bn, 64, 0, stream>>>(A, theta_w, theta_b, W_w, W_b, Mp);
    apply_kernel<<<dim3(Nn / 256, Bn), 256, 0, stream>>>(target, Mp, out);
}

// Round 2
// 154.008 us; speedup vs baseline: 1.2955x; 1.2955x over previous
//
#include <hip/hip_runtime.h>

// Problem constants
#define Bn  4
#define Cc  64      // channels
#define ICc 32      // inner channels
#define Hh  128
#define Ww  128
#define Nn  (Hh*Ww)     // 16384
#define Hp  (Hh/2)      // 64 pooled rows
#define Wp  (Ww/2)      // 64 pooled cols
#define Mm  (Hp*Wp)     // 4096 pooled positions
#define Sg  8           // gram m-split factor

// ---------------------------------------------------------------------------
// Kernel 1: fused 1x1 conv + 2x2 maxpool for phi (from ref) and g (from ref_align).
// grid (Hp, B, 4): z&1 = input select, z>>1 = ic-half. block 128.
// Thread t: pw = t>>1, row-parity r = t&1; computes 16 conv channels at 2
// horizontal pixels (float2), maxes them, vertical max via shfl pair.
// 1024 blocks -> 4 blocks/CU x 2 waves = 8 waves/CU.
// ---------------------------------------------------------------------------
__global__ __launch_bounds__(128) void conv_pool_kernel(
    const float* __restrict__ ref, const float* __restrict__ ref_align,
    const float* __restrict__ phi_w, const float* __restrict__ phi_b,
    const float* __restrict__ g_w,   const float* __restrict__ g_b,
    float* __restrict__ P, float* __restrict__ G)
{
    const int z   = blockIdx.z;
    const int inp = z & 1;
    const int icb = (z >> 1) * (ICc / 2);   // 0 or 16
    const float* in   = inp ? ref_align : ref;
    const float* wmat = (inp ? g_w : phi_w) + icb * Cc;
    const float* bias = (inp ? g_b : phi_b) + icb;
    float* outp       = inp ? G : P;

    __shared__ float sw[(ICc / 2) * Cc];
    __shared__ float sb[ICc / 2];
    for (int idx = threadIdx.x; idx < (ICc / 2) * Cc; idx += 128) sw[idx] = wmat[idx];
    if (threadIdx.x < ICc / 2) sb[threadIdx.x] = bias[threadIdx.x];
    __syncthreads();

    const int tid = threadIdx.x;
    const int pw  = tid >> 1;
    const int r   = tid & 1;
    const int ph  = blockIdx.x;
    const int b   = blockIdx.y;
    const int hh  = 2 * ph + r;

    const float2* xrow = (const float2*)(in + ((size_t)b * Cc * Hh + hh) * Ww);
    const int cstride2 = (Hh * Ww) / 2;   // channel stride in float2

    float acc0[ICc / 2], acc1[ICc / 2];
    #pragma unroll
    for (int i = 0; i < ICc / 2; ++i) { acc0[i] = sb[i]; acc1[i] = sb[i]; }

    #pragma unroll 4
    for (int c = 0; c < Cc; ++c) {
        float2 v = xrow[c * cstride2 + pw];
        #pragma unroll
        for (int i = 0; i < ICc / 2; ++i) {
            acc0[i] = fmaf(sw[i * Cc + c], v.x, acc0[i]);
            acc1[i] = fmaf(sw[i * Cc + c], v.y, acc1[i]);
        }
    }

    const int m = ph * Wp + pw;
    #pragma unroll
    for (int i = 0; i < ICc / 2; ++i) {
        float mx = fmaxf(acc0[i], acc1[i]);
        mx = fmaxf(mx, __shfl_xor(mx, 1, 64));   // vertical max (pair lanes same wave)
        if (r == 0) outp[((size_t)(b * ICc + icb + i)) * Mm + m] = mx;
    }
}

// ---------------------------------------------------------------------------
// Kernel 2: partial gram. Apart[b,s,i,j] = sum_{m in slice s} G[b,i,m]*P[b,j,m].
// grid (IC, B, Sg) = 1024 blocks, block 256. Slice = Mm/Sg = 512 (2 m/thread).
// ---------------------------------------------------------------------------
__global__ __launch_bounds__(256) void gram_kernel(
    const float* __restrict__ P, const float* __restrict__ G,
    float* __restrict__ Apart)
{
    const int i = blockIdx.x, b = blockIdx.y, s = blockIdx.z;
    const float* Gi = G + ((size_t)(b * ICc + i)) * Mm;
    const float* Pb = P + (size_t)b * ICc * Mm;
    const int mbase = s * (Mm / Sg);

    float acc[ICc];
    #pragma unroll
    for (int j = 0; j < ICc; ++j) acc[j] = 0.f;

    #pragma unroll
    for (int k = 0; k < (Mm / Sg) / 256; ++k) {
        int m = mbase + k * 256 + threadIdx.x;
        float gv = Gi[m];
        #pragma unroll
        for (int j = 0; j < ICc; ++j) acc[j] = fmaf(gv, Pb[j * Mm + m], acc[j]);
    }

    // butterfly reduce across the 64-lane wave
    #pragma unroll
    for (int j = 0; j < ICc; ++j) {
        #pragma unroll
        for (int off = 32; off > 0; off >>= 1)
            acc[j] += __shfl_xor(acc[j], off, 64);
    }

    __shared__ float red[4][ICc];
    const int lane = threadIdx.x & 63, wid = threadIdx.x >> 6;
    if (lane == 0)
        for (int j = 0; j < ICc; ++j) red[wid][j] = acc[j];
    __syncthreads();

    if (threadIdx.x < ICc) {
        float sum = red[0][threadIdx.x] + red[1][threadIdx.x]
                  + red[2][threadIdx.x] + red[3][threadIdx.x];
        Apart[(((size_t)b * Sg + s) * ICc + i) * ICc + threadIdx.x] = sum;
    }
}

// ---------------------------------------------------------------------------
// Kernel 3: per-batch fused matrix  M'[o,c] = (W_w @ (A/N) @ theta_w)[o,c] + (o==c)
//           and bias v[o] = (W_w @ (A/N) @ theta_b)[o] + W_b[o].
// grid B, block 64 (thread = output channel o). Sums the Sg gram partials.
// ---------------------------------------------------------------------------
__global__ __launch_bounds__(64) void combine_kernel(
    const float* __restrict__ Apart, const float* __restrict__ theta_w,
    const float* __restrict__ theta_b, const float* __restrict__ W_w,
    const float* __restrict__ W_b, float* __restrict__ Mp)
{
    const int b = blockIdx.x, o = threadIdx.x;
    __shared__ float sA[ICc * ICc];
    for (int idx = threadIdx.x; idx < ICc * ICc; idx += 64) {
        float sum = 0.f;
        #pragma unroll
        for (int s = 0; s < Sg; ++s)
            sum += Apart[((size_t)b * Sg + s) * ICc * ICc + idx];
        sA[idx] = sum;
    }
    __syncthreads();

    float T[ICc];
    #pragma unroll
    for (int j = 0; j < ICc; ++j) T[j] = 0.f;
    for (int i = 0; i < ICc; ++i) {
        float wv = W_w[o * ICc + i];
        #pragma unroll
        for (int j = 0; j < ICc; ++j) T[j] = fmaf(wv, sA[i * ICc + j], T[j]);
    }

    const float invN = 1.f / (float)Nn;
    float* Mb = Mp + (size_t)b * (Cc * Cc + Cc);
    for (int c = 0; c < Cc; ++c) {
        float s = 0.f;
        #pragma unroll
        for (int j = 0; j < ICc; ++j) s = fmaf(T[j], theta_w[j * Cc + c], s);
        Mb[o * Cc + c] = s * invN + (o == c ? 1.f : 0.f);
    }
    float v = 0.f;
    #pragma unroll
    for (int j = 0; j < ICc; ++j) v = fmaf(T[j], theta_b[j], v);
    Mb[Cc * Cc + o] = v * invN + W_b[o];
}

// ---------------------------------------------------------------------------
// Kernel 4: out[b,o,n] = sum_c M'_b[o,c]*x[b,c,n] + v_b[o]  (residual in M').
// grid (Nn/512, B, 8): z = 8-channel output group; block 256, float2 positions.
// 1024 blocks -> 4 blocks/CU x 4 waves = 16 waves/CU.
// ---------------------------------------------------------------------------
__global__ __launch_bounds__(256) void apply_kernel(
    const float* __restrict__ x, const float* __restrict__ Mp, float* __restrict__ out)
{
    const int b = blockIdx.y;
    const int obase = blockIdx.z * 8;
    const float* Mb = Mp + (size_t)b * (Cc * Cc + Cc);

    __shared__ float sM[8 * Cc];
    __shared__ float sv[8];
    for (int idx = threadIdx.x; idx < 8 * Cc; idx += 256)
        sM[idx] = Mb[(obase + (idx >> 6)) * Cc + (idx & 63)];
    if (threadIdx.x < 8) sv[threadIdx.x] = Mb[Cc * Cc + obase + threadIdx.x];
    __syncthreads();

    const int n2 = blockIdx.x * 256 + threadIdx.x;      // float2 index
    const float2* xb = (const float2*)(x + (size_t)b * Cc * Nn);
    float2*       ob = (float2*)(out + (size_t)b * Cc * Nn);

    float accx[8], accy[8];
    #pragma unroll
    for (int i = 0; i < 8; ++i) { accx[i] = sv[i]; accy[i] = sv[i]; }

    #pragma unroll 4
    for (int c = 0; c < Cc; ++c) {
        float2 xv = xb[c * (Nn / 2) + n2];
        #pragma unroll
        for (int i = 0; i < 8; ++i) {
            float w = sM[i * Cc + c];          // wave-broadcast, conflict-free
            accx[i] = fmaf(w, xv.x, accx[i]);
            accy[i] = fmaf(w, xv.y, accy[i]);
        }
    }

    #pragma unroll
    for (int i = 0; i < 8; ++i) {
        float2 o2; o2.x = accx[i]; o2.y = accy[i];
        ob[(obase + i) * (Nn / 2) + n2] = o2;
    }
}

// ---------------------------------------------------------------------------
extern "C" void kernel_launch(void* const* d_in, const int* in_sizes, int n_in,
                              void* d_out, int out_size, void* d_ws, size_t ws_size,
                              hipStream_t stream) {
    const float* target    = (const float*)d_in[0];
    const float* ref       = (const float*)d_in[1];
    const float* ref_align = (const float*)d_in[2];
    const float* theta_w   = (const float*)d_in[3];
    const float* theta_b   = (const float*)d_in[4];
    const float* phi_w     = (const float*)d_in[5];
    const float* phi_b     = (const float*)d_in[6];
    const float* g_w       = (const float*)d_in[7];
    const float* g_b       = (const float*)d_in[8];
    const float* W_w       = (const float*)d_in[9];
    const float* W_b       = (const float*)d_in[10];
    float* out = (float*)d_out;

    // workspace (floats): P[B*IC*M] | G[B*IC*M] | Apart[B*Sg*IC*IC] | Mp[B*(C*C+C)]
    float* ws    = (float*)d_ws;
    float* P     = ws;
    float* G     = P + (size_t)Bn * ICc * Mm;
    float* Apart = G + (size_t)Bn * ICc * Mm;
    float* Mp    = Apart + (size_t)Bn * Sg * ICc * ICc;

    conv_pool_kernel<<<dim3(Hp, Bn, 4), 128, 0, stream>>>(ref, ref_align,
                                                          phi_w, phi_b, g_w, g_b, P, G);
    gram_kernel<<<dim3(ICc, Bn, Sg), 256, 0, stream>>>(P, G, Apart);
    combine_kernel<<<Bn, 64, 0, stream>>>(Apart, theta_w, theta_b, W_w, W_b, Mp);
    apply_kernel<<<dim3(Nn / 512, Bn, 8), 256, 0, stream>>>(target, Mp, out);
}

// Round 3
// 151.041 us; speedup vs baseline: 1.3210x; 1.0196x over previous
//
#include <hip/hip_runtime.h>

// Problem constants
#define Bn  4
#define Cc  64      // channels
#define ICc 32      // inner channels
#define Hh  128
#define Ww  128
#define Nn  (Hh*Ww)     // 16384
#define Hp  (Hh/2)      // 64 pooled rows
#define Wp  (Ww/2)      // 64 pooled cols
#define Mm  (Hp*Wp)     // 4096 pooled positions
#define Sg  8           // gram m-split factor

// ---------------------------------------------------------------------------
// Kernel 1: fused 1x1 conv + 2x2 maxpool for phi (from ref) and g (from ref_align).
// grid (Hp, B, 8): z&1 = input select, z>>1 = ic-quarter (8 ICs). block 128.
// Thread t: pw = t>>1, row-parity r = t&1; computes 8 conv channels at 2
// horizontal pixels (float2), maxes them, vertical max via shfl pair.
// 2048 blocks x 2 waves -> 16 waves/CU = 4 waves/SIMD.
// ---------------------------------------------------------------------------
__global__ __launch_bounds__(128) void conv_pool_kernel(
    const float* __restrict__ ref, const float* __restrict__ ref_align,
    const float* __restrict__ phi_w, const float* __restrict__ phi_b,
    const float* __restrict__ g_w,   const float* __restrict__ g_b,
    float* __restrict__ P, float* __restrict__ G)
{
    const int z   = blockIdx.z;
    const int inp = z & 1;
    const int icb = (z >> 1) * 8;           // 0,8,16,24
    const float* in   = inp ? ref_align : ref;
    const float* wmat = (inp ? g_w : phi_w) + icb * Cc;
    const float* bias = (inp ? g_b : phi_b) + icb;
    float* outp       = inp ? G : P;

    __shared__ float sw[8 * Cc];
    __shared__ float sb[8];
    for (int idx = threadIdx.x; idx < 8 * Cc; idx += 128) sw[idx] = wmat[idx];
    if (threadIdx.x < 8) sb[threadIdx.x] = bias[threadIdx.x];
    __syncthreads();

    const int tid = threadIdx.x;
    const int pw  = tid >> 1;
    const int r   = tid & 1;
    const int ph  = blockIdx.x;
    const int b   = blockIdx.y;
    const int hh  = 2 * ph + r;

    const float2* xrow = (const float2*)(in + ((size_t)b * Cc * Hh + hh) * Ww);
    const int cstride2 = (Hh * Ww) / 2;   // channel stride in float2

    float acc0[8], acc1[8];
    #pragma unroll
    for (int i = 0; i < 8; ++i) { acc0[i] = sb[i]; acc1[i] = sb[i]; }

    #pragma unroll 8
    for (int c = 0; c < Cc; ++c) {
        float2 v = xrow[c * cstride2 + pw];
        #pragma unroll
        for (int i = 0; i < 8; ++i) {
            acc0[i] = fmaf(sw[i * Cc + c], v.x, acc0[i]);
            acc1[i] = fmaf(sw[i * Cc + c], v.y, acc1[i]);
        }
    }

    const int m = ph * Wp + pw;
    #pragma unroll
    for (int i = 0; i < 8; ++i) {
        float mx = fmaxf(acc0[i], acc1[i]);
        mx = fmaxf(mx, __shfl_xor(mx, 1, 64));   // vertical max (pair lanes same wave)
        if (r == 0) outp[((size_t)(b * ICc + icb + i)) * Mm + m] = mx;
    }
}

// ---------------------------------------------------------------------------
// Kernel 2: partial gram. Apart[b,s,i,j] = sum_{m in slice s} G[b,i,m]*P[b,j,m].
// grid (IC, B, Sg) = 1024 blocks, block 256. Slice = Mm/Sg = 512 (2 m/thread).
// ---------------------------------------------------------------------------
__global__ __launch_bounds__(256) void gram_kernel(
    const float* __restrict__ P, const float* __restrict__ G,
    float* __restrict__ Apart)
{
    const int i = blockIdx.x, b = blockIdx.y, s = blockIdx.z;
    const float* Gi = G + ((size_t)(b * ICc + i)) * Mm;
    const float* Pb = P + (size_t)b * ICc * Mm;
    const int mbase = s * (Mm / Sg);

    float acc[ICc];
    #pragma unroll
    for (int j = 0; j < ICc; ++j) acc[j] = 0.f;

    #pragma unroll
    for (int k = 0; k < (Mm / Sg) / 256; ++k) {
        int m = mbase + k * 256 + threadIdx.x;
        float gv = Gi[m];
        #pragma unroll
        for (int j = 0; j < ICc; ++j) acc[j] = fmaf(gv, Pb[j * Mm + m], acc[j]);
    }

    // butterfly reduce across the 64-lane wave
    #pragma unroll
    for (int j = 0; j < ICc; ++j) {
        #pragma unroll
        for (int off = 32; off > 0; off >>= 1)
            acc[j] += __shfl_xor(acc[j], off, 64);
    }

    __shared__ float red[4][ICc];
    const int lane = threadIdx.x & 63, wid = threadIdx.x >> 6;
    if (lane == 0)
        for (int j = 0; j < ICc; ++j) red[wid][j] = acc[j];
    __syncthreads();

    if (threadIdx.x < ICc) {
        float sum = red[0][threadIdx.x] + red[1][threadIdx.x]
                  + red[2][threadIdx.x] + red[3][threadIdx.x];
        Apart[(((size_t)b * Sg + s) * ICc + i) * ICc + threadIdx.x] = sum;
    }
}

// ---------------------------------------------------------------------------
// Kernel 3: fused combine + apply.
// Each block serves batch b, output group obase = 4*blockIdx.z, positions
// n2 in [blockIdx.x*256, ...). Prologue recomputes its 4 rows of the fused
// matrix M'[o,c] = (W_w @ (A/N) @ theta_w)[o,c] + (o==c) and bias
// v[o] = (W_w @ (A/N) @ theta_b)[o] + W_b[o] from the gram partials.
// grid (Nn/512, B, 16) = 2048 blocks, block 256 -> 32 waves/CU = 8/SIMD.
// ---------------------------------------------------------------------------
__global__ __launch_bounds__(256) void apply_kernel(
    const float* __restrict__ x, const float* __restrict__ Apart,
    const float* __restrict__ theta_w, const float* __restrict__ theta_b,
    const float* __restrict__ W_w,     const float* __restrict__ W_b,
    float* __restrict__ out)
{
    const int b     = blockIdx.y;
    const int obase = blockIdx.z * 4;

    __shared__ float sA[ICc * ICc];   // summed gram, 4 KB
    __shared__ float sT[4 * ICc];     // T rows for our 4 outputs
    __shared__ float sM[4 * Cc];      // fused matrix rows
    __shared__ float sv[4];           // fused bias

    // sum the Sg gram partials
    const float* Ab = Apart + (size_t)b * Sg * ICc * ICc;
    for (int idx = threadIdx.x; idx < ICc * ICc; idx += 256) {
        float sum = 0.f;
        #pragma unroll
        for (int s = 0; s < Sg; ++s) sum += Ab[s * ICc * ICc + idx];
        sA[idx] = sum;
    }
    __syncthreads();

    // T[ol][j] = sum_i W_w[(obase+ol), i] * sA[i][j]
    if (threadIdx.x < 4 * ICc) {
        const int ol = threadIdx.x >> 5, j = threadIdx.x & 31;
        const float* wr = W_w + (obase + ol) * ICc;
        float t = 0.f;
        #pragma unroll
        for (int i = 0; i < ICc; ++i) t = fmaf(wr[i], sA[i * ICc + j], t);
        sT[ol * ICc + j] = t;
    }
    __syncthreads();

    const float invN = 1.f / (float)Nn;
    {   // M'[ol][c] and v[ol]
        const int ol = threadIdx.x >> 6, c = threadIdx.x & 63;
        float s = 0.f;
        #pragma unroll
        for (int j = 0; j < ICc; ++j) s = fmaf(sT[ol * ICc + j], theta_w[j * Cc + c], s);
        sM[ol * Cc + c] = s * invN + ((obase + ol) == c ? 1.f : 0.f);
        if (threadIdx.x < 4) {
            float v = 0.f;
            #pragma unroll
            for (int j = 0; j < ICc; ++j) v = fmaf(sT[threadIdx.x * ICc + j], theta_b[j], v);
            sv[threadIdx.x] = v * invN + W_b[obase + threadIdx.x];
        }
    }
    __syncthreads();

    const int n2 = blockIdx.x * 256 + threadIdx.x;      // float2 index
    const float2* xb = (const float2*)(x + (size_t)b * Cc * Nn);
    float2*       ob = (float2*)(out + (size_t)b * Cc * Nn);

    float accx[4], accy[4];
    #pragma unroll
    for (int i = 0; i < 4; ++i) { accx[i] = sv[i]; accy[i] = sv[i]; }

    #pragma unroll 8
    for (int c = 0; c < Cc; ++c) {
        float2 xv = xb[c * (Nn / 2) + n2];
        #pragma unroll
        for (int i = 0; i < 4; ++i) {
            float w = sM[i * Cc + c];          // wave-broadcast, conflict-free
            accx[i] = fmaf(w, xv.x, accx[i]);
            accy[i] = fmaf(w, xv.y, accy[i]);
        }
    }

    #pragma unroll
    for (int i = 0; i < 4; ++i) {
        float2 o2; o2.x = accx[i]; o2.y = accy[i];
        ob[(obase + i) * (Nn / 2) + n2] = o2;
    }
}

// ---------------------------------------------------------------------------
extern "C" void kernel_launch(void* const* d_in, const int* in_sizes, int n_in,
                              void* d_out, int out_size, void* d_ws, size_t ws_size,
                              hipStream_t stream) {
    const float* target    = (const float*)d_in[0];
    const float* ref       = (const float*)d_in[1];
    const float* ref_align = (const float*)d_in[2];
    const float* theta_w   = (const float*)d_in[3];
    const float* theta_b   = (const float*)d_in[4];
    const float* phi_w     = (const float*)d_in[5];
    const float* phi_b     = (const float*)d_in[6];
    const float* g_w       = (const float*)d_in[7];
    const float* g_b       = (const float*)d_in[8];
    const float* W_w       = (const float*)d_in[9];
    const float* W_b       = (const float*)d_in[10];
    float* out = (float*)d_out;

    // workspace (floats): P[B*IC*M] | G[B*IC*M] | Apart[B*Sg*IC*IC]
    float* ws    = (float*)d_ws;
    float* P     = ws;
    float* G     = P + (size_t)Bn * ICc * Mm;
    float* Apart = G + (size_t)Bn * ICc * Mm;

    conv_pool_kernel<<<dim3(Hp, Bn, 8), 128, 0, stream>>>(ref, ref_align,
                                                          phi_w, phi_b, g_w, g_b, P, G);
    gram_kernel<<<dim3(ICc, Bn, Sg), 256, 0, stream>>>(P, G, Apart);
    apply_kernel<<<dim3(Nn / 512, Bn, 16), 256, 0, stream>>>(target, Apart,
                                                             theta_w, theta_b,
                                                             W_w, W_b, out);
}